// Round 5
// baseline (9783.033 us; speedup 1.0000x reference)
//
#include <hip/hip_runtime.h>
#include <hip/hip_bf16.h>
#include <math.h>

#define NNODES 50000
#define NEDGES 1600000
#define NODEF 92
#define EDGEF 41
#define HID 128
#define NCONV 3
#define NGRAPHS 256
#define ZDIM 297            // 2*HID + EDGEF
#define KPAD 320            // pad K to 10 MFMA steps of 32
#define KSTEPS 10
#define ZLD 328             // LDS leading dim in f16
#define ME 32               // edges per block

typedef _Float16 half8 __attribute__((ext_vector_type(8)));
typedef _Float16 half4 __attribute__((ext_vector_type(4)));
typedef float f32x4 __attribute__((ext_vector_type(4)));

__device__ __forceinline__ float softplus_f(float x) {
    return fmaxf(x, 0.f) + __logf(1.f + __expf(-fabsf(x)));
}
__device__ __forceinline__ float sigmoid_f(float x) {
    return __builtin_amdgcn_rcpf(1.f + __expf(-x));
}

// ---------------- dst counting sort (once per launch; edges constant across layers) ----
__global__ void hist_kernel(const int* __restrict__ ei, int* __restrict__ counts) {
    const int e = blockIdx.x * blockDim.x + threadIdx.x;
    if (e < NEDGES) atomicAdd(&counts[ei[e]], 1);
}

#define SCAN_T 1024
#define SCAN_CH 49          // 1024*49 = 50176 >= NNODES
__global__ __launch_bounds__(1024) void scan_kernel(int* __restrict__ counts) {
    __shared__ int part[SCAN_T];
    const int t = threadIdx.x;
    const int base = t * SCAN_CH;
    int s = 0;
    for (int i = 0; i < SCAN_CH; ++i) {
        const int idx = base + i;
        if (idx < NNODES) s += counts[idx];
    }
    part[t] = s;
    __syncthreads();
    for (int off = 1; off < SCAN_T; off <<= 1) {
        const int v = (t >= off) ? part[t - off] : 0;
        __syncthreads();
        part[t] += v;
        __syncthreads();
    }
    int run = (t > 0) ? part[t - 1] : 0;    // exclusive prefix of this chunk
    for (int i = 0; i < SCAN_CH; ++i) {
        const int idx = base + i;
        if (idx < NNODES) { const int c = counts[idx]; counts[idx] = run; run += c; }
    }
}

__global__ void scatter_kernel(const int* __restrict__ ei, int* __restrict__ offs,
                               int* __restrict__ perm) {
    const int e = blockIdx.x * blockDim.x + threadIdx.x;
    if (e >= NEDGES) return;
    const int d = ei[e];
    const int pos = atomicAdd(&offs[d], 1);
    perm[pos] = e;
}

// ---------------- weight fragment prep (unchanged, proven) ----------------
__global__ void prep_wfrag(const float* __restrict__ msg_w, const float* __restrict__ gate_w,
                           half8* __restrict__ wf) {
    const int idx = blockIdx.x * blockDim.x + threadIdx.x;
    const int total = NCONV * 16 * KSTEPS * 64;
    if (idx >= total) return;
    const int lane = idx & 63;
    const int rest = idx >> 6;
    const int ks = rest % KSTEPS;
    const int gl = rest / KSTEPS;
    const int g = gl & 15;
    const int l = gl >> 4;
    const int branch = g & 1;
    const int j = (g >> 2) * 32 + ((g >> 1) & 1) * 16 + (lane & 15);
    const int k0 = ks * 32 + (lane >> 4) * 8;
    const float* W = branch ? gate_w : msg_w;
    half8 v;
    #pragma unroll
    for (int jj = 0; jj < 8; ++jj) {
        const int k = k0 + jj;
        const float f = (k < ZDIM) ? W[((size_t)l * ZDIM + k) * HID + j] : 0.f;
        v[jj] = (_Float16)f;
    }
    wf[idx] = v;
}

__global__ void embed_kernel(const float* __restrict__ x, const float* __restrict__ w,
                             const float* __restrict__ b, _Float16* __restrict__ h) {
    __shared__ float xs[NODEF];
    const int n = blockIdx.x;
    const int j = threadIdx.x;
    if (j < NODEF) xs[j] = x[(size_t)n * NODEF + j];
    __syncthreads();
    float acc = b[j];
    #pragma unroll 4
    for (int k = 0; k < NODEF; ++k) acc = fmaf(xs[k], w[k * HID + j], acc);
    h[(size_t)n * HID + j] = (_Float16)acc;
}

// ---------------- edge kernel: dst-sorted gather, PROVEN direct-atomic epilogue ----------
__global__ __launch_bounds__(256) void edge_mfma_kernel(
    const _Float16* __restrict__ h, const int* __restrict__ ei,
    const int* __restrict__ perm,
    const float* __restrict__ ea, const half8* __restrict__ wf,
    const float* __restrict__ bm, const float* __restrict__ bg,
    float* __restrict__ aggr) {
    __shared__ __align__(16) _Float16 zs[ME][ZLD];        // 21 KB
    __shared__ const half8* shp[2 * ME];                  // gather row pointers
    __shared__ float* sbase[ME];                          // aggr row bases
    __shared__ int sperm[ME];

    const int t = threadIdx.x;
    const int eb = blockIdx.x * ME;

    // wave 0: row pointers through the sorted permutation
    if (t < 64) {
        const int p = perm[eb + (t & (ME - 1))];
        if (t < ME) {
            sperm[t] = p;
            const int d = ei[p];                                  // dst
            shp[t] = (const half8*)(h + (size_t)d * HID);
            sbase[t] = aggr + (size_t)d * HID;
        } else {
            shp[t] = (const half8*)(h + (size_t)ei[NEDGES + p] * HID);  // src
        }
    }
    __syncthreads();

    // ---- stage z into LDS (h already f16: 16 half8 per row per side) ----
    #pragma unroll
    for (int i = 0; i < 4; ++i) {
        const int idx = t + 256 * i;       // 0..1023
        const int r = idx >> 5;            // edge row 0..31
        const int c = idx & 31;            // half8 chunk 0..31
        const half8 v = (c < 16) ? shp[r][c] : shp[ME + r][c - 16];
        *(half8*)&zs[r][c * 8] = v;
    }
    // edge-attr (gathered through perm) + zero pad: k 256..319
    #pragma unroll
    for (int i = 0; i < 8; ++i) {
        const int idx = t + 256 * i;
        const int r = idx >> 6;
        const int k = 256 + (idx & 63);
        float f = 0.f;
        if (k < ZDIM) f = ea[(size_t)sperm[r] * EDGEF + (k - 256)];
        zs[r][k] = (_Float16)f;
    }
    __syncthreads();

    // ---- MFMA: [32 x KPAD] @ [KPAD x 256] ----
    const int wave = t >> 6;
    const int lane = t & 63;
    const int arow = lane & 15;
    const int koff = (lane >> 4) * 8;

    f32x4 acc[2][4];
    #pragma unroll
    for (int m = 0; m < 2; ++m)
        #pragma unroll
        for (int n = 0; n < 4; ++n) acc[m][n] = (f32x4){0.f, 0.f, 0.f, 0.f};

    const half8* wfw = wf + (size_t)(wave * 4) * KSTEPS * 64 + lane;
    #pragma unroll 2
    for (int ks = 0; ks < KSTEPS; ++ks) {
        const int kb = ks * 32 + koff;
        const half8 a0 = *(const half8*)&zs[arow][kb];
        const half8 a1 = *(const half8*)&zs[16 + arow][kb];
        #pragma unroll
        for (int nt = 0; nt < 4; ++nt) {
            const half8 b = wfw[(size_t)(nt * KSTEPS + ks) * 64];
            acc[0][nt] = __builtin_amdgcn_mfma_f32_16x16x32_f16(a0, b, acc[0][nt], 0, 0, 0);
            acc[1][nt] = __builtin_amdgcn_mfma_f32_16x16x32_f16(a1, b, acc[1][nt], 0, 0, 0);
        }
    }

    // ---- epilogue: gate*msg, direct atomic scatter-add (proven round-0 path) ----
    const int j0 = wave * 32 + (lane & 15);
    const float bm0 = bm[j0], bm1 = bm[j0 + 16];
    const float bg0 = bg[j0], bg1 = bg[j0 + 16];
    #pragma unroll
    for (int m = 0; m < 2; ++m) {
        #pragma unroll
        for (int r = 0; r < 4; ++r) {
            const int row = m * 16 + (lane >> 4) * 4 + r;
            float* base = sbase[row];
            {
                const float gate = sigmoid_f(acc[m][0][r] + bm0);
                const float msg = softplus_f(acc[m][1][r] + bg0);
                atomicAdd(base + j0, gate * msg);
            }
            {
                const float gate = sigmoid_f(acc[m][2][r] + bm1);
                const float msg = softplus_f(acc[m][3][r] + bg1);
                atomicAdd(base + j0 + 16, gate * msg);
            }
        }
    }
}

__global__ void update_kernel(_Float16* __restrict__ h, const float* __restrict__ aggr) {
    const size_t idx = (size_t)blockIdx.x * blockDim.x + threadIdx.x;   // half8 index
    half8 hv = ((const half8*)h)[idx];
    const f32x4 a0 = ((const f32x4*)aggr)[2 * idx];
    const f32x4 a1 = ((const f32x4*)aggr)[2 * idx + 1];
    #pragma unroll
    for (int j = 0; j < 4; ++j) hv[j] = (_Float16)softplus_f((float)hv[j] + a0[j]);
    #pragma unroll
    for (int j = 0; j < 4; ++j) hv[4 + j] = (_Float16)softplus_f((float)hv[4 + j] + a1[j]);
    ((half8*)h)[idx] = hv;
}

__global__ void readout_kernel(const _Float16* __restrict__ h, const int* __restrict__ batch,
                               const float* __restrict__ ro1w, const float* __restrict__ ro1b,
                               const float* __restrict__ ro2w, const float* __restrict__ ro2b,
                               float* __restrict__ out) {
    __shared__ float pooled[HID];
    __shared__ float red[HID];
    __shared__ int range[2];
    const int g = blockIdx.x, j = threadIdx.x;
    if (j == 0) {
        int lo = 0, hi = NNODES;
        while (lo < hi) { int mid = (lo + hi) >> 1; if (batch[mid] < g) lo = mid + 1; else hi = mid; }
        range[0] = lo;
        hi = NNODES;
        while (lo < hi) { int mid = (lo + hi) >> 1; if (batch[mid] < g + 1) lo = mid + 1; else hi = mid; }
        range[1] = lo;
    }
    __syncthreads();
    const int start = range[0], end = range[1];
    float s = 0.f;
    for (int n = start; n < end; ++n) s += (float)h[(size_t)n * HID + j];
    const float cnt = (float)(end - start);
    pooled[j] = s / fmaxf(cnt, 1.f);
    __syncthreads();
    float acc = ro1b[j];
    #pragma unroll 4
    for (int k = 0; k < HID; ++k) acc = fmaf(pooled[k], ro1w[k * HID + j], acc);
    red[j] = softplus_f(acc) * ro2w[j];
    __syncthreads();
    for (int sdt = 64; sdt > 0; sdt >>= 1) {
        if (j < sdt) red[j] += red[j + sdt];
        __syncthreads();
    }
    if (j == 0) out[g] = red[0] + ro2b[0];
}

extern "C" void kernel_launch(void* const* d_in, const int* in_sizes, int n_in,
                              void* d_out, int out_size, void* d_ws, size_t ws_size,
                              hipStream_t stream) {
    (void)in_sizes; (void)n_in; (void)out_size; (void)ws_size;
    const float* x      = (const float*)d_in[0];
    const int*   ei     = (const int*)d_in[1];
    const float* ea     = (const float*)d_in[2];
    const int*   batch  = (const int*)d_in[3];
    const float* emb_w  = (const float*)d_in[4];
    const float* emb_b  = (const float*)d_in[5];
    const float* msg_w  = (const float*)d_in[6];
    const float* msg_b  = (const float*)d_in[7];
    const float* gate_w = (const float*)d_in[8];
    const float* gate_b = (const float*)d_in[9];
    const float* ro1w   = (const float*)d_in[10];
    const float* ro1b   = (const float*)d_in[11];
    const float* ro2w   = (const float*)d_in[12];
    const float* ro2b   = (const float*)d_in[13];
    float* out = (float*)d_out;

    // workspace: h(f16) 12.8MB + aggr(f32) 25.6MB + wfrag 0.49MB + perm 6.4MB = 45.3MB
    // (proven on-harness budget: >=51.7MB from round-1 passing run)
    _Float16* h  = (_Float16*)d_ws;
    float* aggr  = (float*)(h + (size_t)NNODES * HID);
    half8* wfrag = (half8*)(aggr + (size_t)NNODES * HID);
    int* perm    = (int*)(wfrag + (size_t)NCONV * 16 * KSTEPS * 64);
    int* counts  = (int*)aggr;   // aliased: sort finishes before aggr's first memset

    // one-time dst counting sort of edges (produces perm only)
    hipMemsetAsync(counts, 0, (size_t)NNODES * sizeof(int), stream);
    hist_kernel<<<(NEDGES + 255) / 256, 256, 0, stream>>>(ei, counts);
    scan_kernel<<<1, SCAN_T, 0, stream>>>(counts);
    scatter_kernel<<<(NEDGES + 255) / 256, 256, 0, stream>>>(ei, counts, perm);

    const int wtotal = NCONV * 16 * KSTEPS * 64;
    prep_wfrag<<<(wtotal + 255) / 256, 256, 0, stream>>>(msg_w, gate_w, wfrag);
    embed_kernel<<<NNODES, HID, 0, stream>>>(x, emb_w, emb_b, h);

    for (int l = 0; l < NCONV; ++l) {
        hipMemsetAsync(aggr, 0, (size_t)NNODES * HID * sizeof(float), stream);
        edge_mfma_kernel<<<NEDGES / ME, 256, 0, stream>>>(
            h, ei, perm, ea, wfrag + (size_t)l * 16 * KSTEPS * 64,
            msg_b + l * HID, gate_b + l * HID, aggr);
        update_kernel<<<((size_t)NNODES * HID / 8) / 256, 256, 0, stream>>>(h, aggr);
    }

    readout_kernel<<<NGRAPHS, HID, 0, stream>>>(h, batch, ro1w, ro1b, ro2w, ro2b, out);
}

// Round 6
// 2939.963 us; speedup vs baseline: 3.3276x; 3.3276x over previous
//
#include <hip/hip_runtime.h>
#include <hip/hip_bf16.h>
#include <math.h>

#define NNODES 50000
#define NEDGES 1600000
#define NODEF 92
#define EDGEF 41
#define HID 128
#define NCONV 3
#define NGRAPHS 256
#define ZDIM 297            // 2*HID + EDGEF
#define KPAD 320            // pad K to 10 MFMA steps of 32
#define KSTEPS 10
#define ZLD 328             // LDS leading dim in f16
#define ME 32               // edges per block

typedef _Float16 half8 __attribute__((ext_vector_type(8)));
typedef _Float16 half4 __attribute__((ext_vector_type(4)));
typedef float f32x4 __attribute__((ext_vector_type(4)));

__device__ __forceinline__ float softplus_f(float x) {
    return fmaxf(x, 0.f) + __logf(1.f + __expf(-fabsf(x)));
}
__device__ __forceinline__ float sigmoid_f(float x) {
    return __builtin_amdgcn_rcpf(1.f + __expf(-x));
}

// ---------------- dst counting sort (once per launch; edges constant across layers) ----
__global__ void hist_kernel(const int* __restrict__ ei, int* __restrict__ counts) {
    const int e = blockIdx.x * blockDim.x + threadIdx.x;
    if (e < NEDGES) atomicAdd(&counts[ei[e]], 1);
}

#define SCAN_T 1024
#define SCAN_CH 49          // 1024*49 = 50176 >= NNODES
__global__ __launch_bounds__(1024) void scan_kernel(int* __restrict__ counts) {
    __shared__ int part[SCAN_T];
    const int t = threadIdx.x;
    const int base = t * SCAN_CH;
    int s = 0;
    for (int i = 0; i < SCAN_CH; ++i) {
        const int idx = base + i;
        if (idx < NNODES) s += counts[idx];
    }
    part[t] = s;
    __syncthreads();
    for (int off = 1; off < SCAN_T; off <<= 1) {
        const int v = (t >= off) ? part[t - off] : 0;
        __syncthreads();
        part[t] += v;
        __syncthreads();
    }
    int run = (t > 0) ? part[t - 1] : 0;    // exclusive prefix of this chunk
    for (int i = 0; i < SCAN_CH; ++i) {
        const int idx = base + i;
        if (idx < NNODES) { const int c = counts[idx]; counts[idx] = run; run += c; }
    }
}

__global__ void scatter_kernel(const int* __restrict__ ei, int* __restrict__ offs,
                               int* __restrict__ perm) {
    const int e = blockIdx.x * blockDim.x + threadIdx.x;
    if (e >= NEDGES) return;
    const int d = ei[e];
    const int pos = atomicAdd(&offs[d], 1);
    perm[pos] = e;
}

// ---------------- weight fragment prep (unchanged, proven) ----------------
__global__ void prep_wfrag(const float* __restrict__ msg_w, const float* __restrict__ gate_w,
                           half8* __restrict__ wf) {
    const int idx = blockIdx.x * blockDim.x + threadIdx.x;
    const int total = NCONV * 16 * KSTEPS * 64;
    if (idx >= total) return;
    const int lane = idx & 63;
    const int rest = idx >> 6;
    const int ks = rest % KSTEPS;
    const int gl = rest / KSTEPS;
    const int g = gl & 15;
    const int l = gl >> 4;
    const int branch = g & 1;
    const int j = (g >> 2) * 32 + ((g >> 1) & 1) * 16 + (lane & 15);
    const int k0 = ks * 32 + (lane >> 4) * 8;
    const float* W = branch ? gate_w : msg_w;
    half8 v;
    #pragma unroll
    for (int jj = 0; jj < 8; ++jj) {
        const int k = k0 + jj;
        const float f = (k < ZDIM) ? W[((size_t)l * ZDIM + k) * HID + j] : 0.f;
        v[jj] = (_Float16)f;
    }
    wf[idx] = v;
}

__global__ void embed_kernel(const float* __restrict__ x, const float* __restrict__ w,
                             const float* __restrict__ b, _Float16* __restrict__ h) {
    __shared__ float xs[NODEF];
    const int n = blockIdx.x;
    const int j = threadIdx.x;
    if (j < NODEF) xs[j] = x[(size_t)n * NODEF + j];
    __syncthreads();
    float acc = b[j];
    #pragma unroll 4
    for (int k = 0; k < NODEF; ++k) acc = fmaf(xs[k], w[k * HID + j], acc);
    h[(size_t)n * HID + j] = (_Float16)acc;
}

// ---------------- edge kernel: dst-sorted gather, LDS column-walk reduction ----------
__global__ __launch_bounds__(256) void edge_mfma_kernel(
    const _Float16* __restrict__ h, const int* __restrict__ ei,
    const int* __restrict__ perm,
    const float* __restrict__ ea, const half8* __restrict__ wf,
    const float* __restrict__ bm, const float* __restrict__ bg,
    float* __restrict__ aggr) {
    __shared__ __align__(16) _Float16 zs[ME][ZLD];        // 21 KB
    __shared__ const half8* shp[2 * ME];                  // gather row pointers
    __shared__ float laggr[ME][HID + 4];                  // 16.5 KB contrib store (non-atomic)
    __shared__ int sdsts[ME];                             // dst node ids (sorted)
    __shared__ int sperm[ME];

    const int t = threadIdx.x;
    const int eb = blockIdx.x * ME;

    // wave 0: row pointers through the sorted permutation (round-5 proven structure)
    if (t < 64) {
        const int p = perm[eb + (t & (ME - 1))];
        if (t < ME) {
            sperm[t] = p;
            const int d = ei[p];                                  // dst
            sdsts[t] = d;
            shp[t] = (const half8*)(h + (size_t)d * HID);
        } else {
            shp[t] = (const half8*)(h + (size_t)ei[NEDGES + p] * HID);  // src
        }
    }
    __syncthreads();

    // ---- stage z into LDS (h already f16: 16 half8 per row per side) ----
    #pragma unroll
    for (int i = 0; i < 4; ++i) {
        const int idx = t + 256 * i;       // 0..1023
        const int r = idx >> 5;            // edge row 0..31
        const int c = idx & 31;            // half8 chunk 0..31
        const half8 v = (c < 16) ? shp[r][c] : shp[ME + r][c - 16];
        *(half8*)&zs[r][c * 8] = v;
    }
    // edge-attr (gathered through perm) + zero pad: k 256..319
    #pragma unroll
    for (int i = 0; i < 8; ++i) {
        const int idx = t + 256 * i;
        const int r = idx >> 6;
        const int k = 256 + (idx & 63);
        float f = 0.f;
        if (k < ZDIM) f = ea[(size_t)sperm[r] * EDGEF + (k - 256)];
        zs[r][k] = (_Float16)f;
    }
    __syncthreads();

    // ---- MFMA: [32 x KPAD] @ [KPAD x 256] ----
    const int wave = t >> 6;
    const int lane = t & 63;
    const int arow = lane & 15;
    const int koff = (lane >> 4) * 8;

    f32x4 acc[2][4];
    #pragma unroll
    for (int m = 0; m < 2; ++m)
        #pragma unroll
        for (int n = 0; n < 4; ++n) acc[m][n] = (f32x4){0.f, 0.f, 0.f, 0.f};

    const half8* wfw = wf + (size_t)(wave * 4) * KSTEPS * 64 + lane;
    #pragma unroll 2
    for (int ks = 0; ks < KSTEPS; ++ks) {
        const int kb = ks * 32 + koff;
        const half8 a0 = *(const half8*)&zs[arow][kb];
        const half8 a1 = *(const half8*)&zs[16 + arow][kb];
        #pragma unroll
        for (int nt = 0; nt < 4; ++nt) {
            const half8 b = wfw[(size_t)(nt * KSTEPS + ks) * 64];
            acc[0][nt] = __builtin_amdgcn_mfma_f32_16x16x32_f16(a0, b, acc[0][nt], 0, 0, 0);
            acc[1][nt] = __builtin_amdgcn_mfma_f32_16x16x32_f16(a1, b, acc[1][nt], 0, 0, 0);
        }
    }

    // ---- epilogue A: gate*msg -> laggr, NON-atomic (each (row,col) written once) ----
    const int j0 = wave * 32 + (lane & 15);
    const float bm0 = bm[j0], bm1 = bm[j0 + 16];
    const float bg0 = bg[j0], bg1 = bg[j0 + 16];
    #pragma unroll
    for (int m = 0; m < 2; ++m) {
        #pragma unroll
        for (int r = 0; r < 4; ++r) {
            const int row = m * 16 + (lane >> 4) * 4 + r;
            {
                const float gate = sigmoid_f(acc[m][0][r] + bm0);
                const float msg = softplus_f(acc[m][1][r] + bg0);
                laggr[row][j0] = gate * msg;
            }
            {
                const float gate = sigmoid_f(acc[m][2][r] + bm1);
                const float msg = softplus_f(acc[m][3][r] + bg1);
                laggr[row][j0 + 16] = gate * msg;
            }
        }
    }
    __syncthreads();

    // ---- epilogue B: column-walk segment reduce, one atomic per (segment-run, col) ----
    // 256 threads = 128 columns x 2 row-halves of 16. A dst run crossing the
    // half boundary flushes twice (both atomic) - still correct.
    {
        const int col = t & 127;
        const int r0 = (t >> 7) * 16;
        float s = 0.f;
        #pragma unroll
        for (int r = r0; r < r0 + 16; ++r) {
            s += laggr[r][col];
            if ((r == r0 + 15) || (sdsts[r + 1] != sdsts[r])) {   // short-circuit: no OOB
                atomicAdd(aggr + (size_t)sdsts[r] * HID + col, s);
                s = 0.f;
            }
        }
    }
}

__global__ void update_kernel(_Float16* __restrict__ h, const float* __restrict__ aggr) {
    const size_t idx = (size_t)blockIdx.x * blockDim.x + threadIdx.x;   // half8 index
    half8 hv = ((const half8*)h)[idx];
    const f32x4 a0 = ((const f32x4*)aggr)[2 * idx];
    const f32x4 a1 = ((const f32x4*)aggr)[2 * idx + 1];
    #pragma unroll
    for (int j = 0; j < 4; ++j) hv[j] = (_Float16)softplus_f((float)hv[j] + a0[j]);
    #pragma unroll
    for (int j = 0; j < 4; ++j) hv[4 + j] = (_Float16)softplus_f((float)hv[4 + j] + a1[j]);
    ((half8*)h)[idx] = hv;
}

__global__ void readout_kernel(const _Float16* __restrict__ h, const int* __restrict__ batch,
                               const float* __restrict__ ro1w, const float* __restrict__ ro1b,
                               const float* __restrict__ ro2w, const float* __restrict__ ro2b,
                               float* __restrict__ out) {
    __shared__ float pooled[HID];
    __shared__ float red[HID];
    __shared__ int range[2];
    const int g = blockIdx.x, j = threadIdx.x;
    if (j == 0) {
        int lo = 0, hi = NNODES;
        while (lo < hi) { int mid = (lo + hi) >> 1; if (batch[mid] < g) lo = mid + 1; else hi = mid; }
        range[0] = lo;
        hi = NNODES;
        while (lo < hi) { int mid = (lo + hi) >> 1; if (batch[mid] < g + 1) lo = mid + 1; else hi = mid; }
        range[1] = lo;
    }
    __syncthreads();
    const int start = range[0], end = range[1];
    float s = 0.f;
    for (int n = start; n < end; ++n) s += (float)h[(size_t)n * HID + j];
    const float cnt = (float)(end - start);
    pooled[j] = s / fmaxf(cnt, 1.f);
    __syncthreads();
    float acc = ro1b[j];
    #pragma unroll 4
    for (int k = 0; k < HID; ++k) acc = fmaf(pooled[k], ro1w[k * HID + j], acc);
    red[j] = softplus_f(acc) * ro2w[j];
    __syncthreads();
    for (int sdt = 64; sdt > 0; sdt >>= 1) {
        if (j < sdt) red[j] += red[j + sdt];
        __syncthreads();
    }
    if (j == 0) out[g] = red[0] + ro2b[0];
}

extern "C" void kernel_launch(void* const* d_in, const int* in_sizes, int n_in,
                              void* d_out, int out_size, void* d_ws, size_t ws_size,
                              hipStream_t stream) {
    (void)in_sizes; (void)n_in; (void)out_size; (void)ws_size;
    const float* x      = (const float*)d_in[0];
    const int*   ei     = (const int*)d_in[1];
    const float* ea     = (const float*)d_in[2];
    const int*   batch  = (const int*)d_in[3];
    const float* emb_w  = (const float*)d_in[4];
    const float* emb_b  = (const float*)d_in[5];
    const float* msg_w  = (const float*)d_in[6];
    const float* msg_b  = (const float*)d_in[7];
    const float* gate_w = (const float*)d_in[8];
    const float* gate_b = (const float*)d_in[9];
    const float* ro1w   = (const float*)d_in[10];
    const float* ro1b   = (const float*)d_in[11];
    const float* ro2w   = (const float*)d_in[12];
    const float* ro2b   = (const float*)d_in[13];
    float* out = (float*)d_out;

    // workspace: h(f16) 12.8MB + aggr(f32) 25.6MB + wfrag 0.49MB + perm 6.4MB = 45.3MB
    _Float16* h  = (_Float16*)d_ws;
    float* aggr  = (float*)(h + (size_t)NNODES * HID);
    half8* wfrag = (half8*)(aggr + (size_t)NNODES * HID);
    int* perm    = (int*)(wfrag + (size_t)NCONV * 16 * KSTEPS * 64);
    int* counts  = (int*)aggr;   // aliased: sort finishes before aggr's first memset

    // one-time dst counting sort of edges (produces perm only)
    hipMemsetAsync(counts, 0, (size_t)NNODES * sizeof(int), stream);
    hist_kernel<<<(NEDGES + 255) / 256, 256, 0, stream>>>(ei, counts);
    scan_kernel<<<1, SCAN_T, 0, stream>>>(counts);
    scatter_kernel<<<(NEDGES + 255) / 256, 256, 0, stream>>>(ei, counts, perm);

    const int wtotal = NCONV * 16 * KSTEPS * 64;
    prep_wfrag<<<(wtotal + 255) / 256, 256, 0, stream>>>(msg_w, gate_w, wfrag);
    embed_kernel<<<NNODES, HID, 0, stream>>>(x, emb_w, emb_b, h);

    for (int l = 0; l < NCONV; ++l) {
        hipMemsetAsync(aggr, 0, (size_t)NNODES * HID * sizeof(float), stream);
        edge_mfma_kernel<<<NEDGES / ME, 256, 0, stream>>>(
            h, ei, perm, ea, wfrag + (size_t)l * 16 * KSTEPS * 64,
            msg_b + l * HID, gate_b + l * HID, aggr);
        update_kernel<<<((size_t)NNODES * HID / 8) / 256, 256, 0, stream>>>(h, aggr);
    }

    readout_kernel<<<NGRAPHS, HID, 0, stream>>>(h, batch, ro1w, ro1b, ro2w, ro2b, out);
}

// Round 7
// 2683.124 us; speedup vs baseline: 3.6461x; 1.0957x over previous
//
#include <hip/hip_runtime.h>
#include <hip/hip_bf16.h>
#include <math.h>

#define NNODES 50000
#define NEDGES 1600000
#define NODEF 92
#define EDGEF 41
#define HID 128
#define NCONV 3
#define NGRAPHS 256
#define ZDIM 297            // 2*HID + EDGEF
#define KPAD 320            // pad K to 10 MFMA steps of 32
#define KSTEPS 10
#define ZLD 328             // LDS leading dim in f16
#define ME 32               // edges per block

typedef _Float16 half8 __attribute__((ext_vector_type(8)));
typedef _Float16 half4 __attribute__((ext_vector_type(4)));
typedef float f32x4 __attribute__((ext_vector_type(4)));

__device__ __forceinline__ float softplus_f(float x) {
    return fmaxf(x, 0.f) + __logf(1.f + __expf(-fabsf(x)));
}
__device__ __forceinline__ float sigmoid_f(float x) {
    return __builtin_amdgcn_rcpf(1.f + __expf(-x));
}

// ---------------- dst counting sort (once per launch; edges constant across layers) ----
__global__ void hist_kernel(const int* __restrict__ ei, int* __restrict__ counts) {
    const int e = blockIdx.x * blockDim.x + threadIdx.x;
    if (e < NEDGES) atomicAdd(&counts[ei[e]], 1);
}

#define SCAN_T 1024
#define SCAN_CH 49          // 1024*49 = 50176 >= NNODES
__global__ __launch_bounds__(1024) void scan_kernel(int* __restrict__ counts) {
    __shared__ int part[SCAN_T];
    const int t = threadIdx.x;
    const int base = t * SCAN_CH;
    int s = 0;
    for (int i = 0; i < SCAN_CH; ++i) {
        const int idx = base + i;
        if (idx < NNODES) s += counts[idx];
    }
    part[t] = s;
    __syncthreads();
    for (int off = 1; off < SCAN_T; off <<= 1) {
        const int v = (t >= off) ? part[t - off] : 0;
        __syncthreads();
        part[t] += v;
        __syncthreads();
    }
    int run = (t > 0) ? part[t - 1] : 0;    // exclusive prefix of this chunk
    for (int i = 0; i < SCAN_CH; ++i) {
        const int idx = base + i;
        if (idx < NNODES) { const int c = counts[idx]; counts[idx] = run; run += c; }
    }
}

__global__ void scatter_kernel(const int* __restrict__ ei, int* __restrict__ offs,
                               int* __restrict__ perm) {
    const int e = blockIdx.x * blockDim.x + threadIdx.x;
    if (e >= NEDGES) return;
    const int d = ei[e];
    const int pos = atomicAdd(&offs[d], 1);
    perm[pos] = e;
}

// ---------------- weight fragment prep (unchanged, proven) ----------------
__global__ void prep_wfrag(const float* __restrict__ msg_w, const float* __restrict__ gate_w,
                           half8* __restrict__ wf) {
    const int idx = blockIdx.x * blockDim.x + threadIdx.x;
    const int total = NCONV * 16 * KSTEPS * 64;
    if (idx >= total) return;
    const int lane = idx & 63;
    const int rest = idx >> 6;
    const int ks = rest % KSTEPS;
    const int gl = rest / KSTEPS;
    const int g = gl & 15;
    const int l = gl >> 4;
    const int branch = g & 1;
    const int j = (g >> 2) * 32 + ((g >> 1) & 1) * 16 + (lane & 15);
    const int k0 = ks * 32 + (lane >> 4) * 8;
    const float* W = branch ? gate_w : msg_w;
    half8 v;
    #pragma unroll
    for (int jj = 0; jj < 8; ++jj) {
        const int k = k0 + jj;
        const float f = (k < ZDIM) ? W[((size_t)l * ZDIM + k) * HID + j] : 0.f;
        v[jj] = (_Float16)f;
    }
    wf[idx] = v;
}

__global__ void embed_kernel(const float* __restrict__ x, const float* __restrict__ w,
                             const float* __restrict__ b, _Float16* __restrict__ h) {
    __shared__ float xs[NODEF];
    const int n = blockIdx.x;
    const int j = threadIdx.x;
    if (j < NODEF) xs[j] = x[(size_t)n * NODEF + j];
    __syncthreads();
    float acc = b[j];
    #pragma unroll 4
    for (int k = 0; k < NODEF; ++k) acc = fmaf(xs[k], w[k * HID + j], acc);
    h[(size_t)n * HID + j] = (_Float16)acc;
}

// ---------------- edge kernel: dst-sorted gather, LDS column-walk reduction ----------
// LDS: zs (staged z, dead after last MFMA ds_read) and laggr (contribs, born
// after MFMA loop) are temporally disjoint -> UNION them. 38.9KB -> ~21.8KB
// per block => 7 blocks/CU instead of 4 (latency hiding).
__global__ __launch_bounds__(256) void edge_mfma_kernel(
    const _Float16* __restrict__ h, const int* __restrict__ ei,
    const int* __restrict__ perm,
    const float* __restrict__ ea, const half8* __restrict__ wf,
    const float* __restrict__ bm, const float* __restrict__ bg,
    float* __restrict__ aggr) {
    __shared__ __align__(16) unsigned char smem_u[ME * ZLD * sizeof(_Float16)]; // 20992 B
    __shared__ const half8* shp[2 * ME];                  // gather row pointers
    __shared__ int sdsts[ME];                             // dst node ids (sorted)
    __shared__ int sperm[ME];

    _Float16 (*zs)[ZLD]     = (_Float16 (*)[ZLD])smem_u;        // phase 1 view
    float (*laggr)[HID + 4] = (float (*)[HID + 4])smem_u;       // phase 2 view (16896 B)

    const int t = threadIdx.x;
    const int eb = blockIdx.x * ME;

    // wave 0: row pointers through the sorted permutation
    if (t < 64) {
        const int p = perm[eb + (t & (ME - 1))];
        if (t < ME) {
            sperm[t] = p;
            const int d = ei[p];                                  // dst
            sdsts[t] = d;
            shp[t] = (const half8*)(h + (size_t)d * HID);
        } else {
            shp[t] = (const half8*)(h + (size_t)ei[NEDGES + p] * HID);  // src
        }
    }
    __syncthreads();

    // ---- stage z into LDS (h already f16: 16 half8 per row per side) ----
    #pragma unroll
    for (int i = 0; i < 4; ++i) {
        const int idx = t + 256 * i;       // 0..1023
        const int r = idx >> 5;            // edge row 0..31
        const int c = idx & 31;            // half8 chunk 0..31
        const half8 v = (c < 16) ? shp[r][c] : shp[ME + r][c - 16];
        *(half8*)&zs[r][c * 8] = v;
    }
    // edge-attr (gathered through perm) + zero pad: k 256..319
    #pragma unroll
    for (int i = 0; i < 8; ++i) {
        const int idx = t + 256 * i;
        const int r = idx >> 6;
        const int k = 256 + (idx & 63);
        float f = 0.f;
        if (k < ZDIM) f = ea[(size_t)sperm[r] * EDGEF + (k - 256)];
        zs[r][k] = (_Float16)f;
    }
    __syncthreads();

    // ---- MFMA: [32 x KPAD] @ [KPAD x 256] ----
    const int wave = t >> 6;
    const int lane = t & 63;
    const int arow = lane & 15;
    const int koff = (lane >> 4) * 8;

    f32x4 acc[2][4];
    #pragma unroll
    for (int m = 0; m < 2; ++m)
        #pragma unroll
        for (int n = 0; n < 4; ++n) acc[m][n] = (f32x4){0.f, 0.f, 0.f, 0.f};

    const half8* wfw = wf + (size_t)(wave * 4) * KSTEPS * 64 + lane;
    #pragma unroll 2
    for (int ks = 0; ks < KSTEPS; ++ks) {
        const int kb = ks * 32 + koff;
        const half8 a0 = *(const half8*)&zs[arow][kb];
        const half8 a1 = *(const half8*)&zs[16 + arow][kb];
        #pragma unroll
        for (int nt = 0; nt < 4; ++nt) {
            const half8 b = wfw[(size_t)(nt * KSTEPS + ks) * 64];
            acc[0][nt] = __builtin_amdgcn_mfma_f32_16x16x32_f16(a0, b, acc[0][nt], 0, 0, 0);
            acc[1][nt] = __builtin_amdgcn_mfma_f32_16x16x32_f16(a1, b, acc[1][nt], 0, 0, 0);
        }
    }
    __syncthreads();   // all zs reads complete before laggr overwrites the union

    // ---- epilogue A: gate*msg -> laggr, NON-atomic (each (row,col) written once) ----
    const int j0 = wave * 32 + (lane & 15);
    const float bm0 = bm[j0], bm1 = bm[j0 + 16];
    const float bg0 = bg[j0], bg1 = bg[j0 + 16];
    #pragma unroll
    for (int m = 0; m < 2; ++m) {
        #pragma unroll
        for (int r = 0; r < 4; ++r) {
            const int row = m * 16 + (lane >> 4) * 4 + r;
            {
                const float gate = sigmoid_f(acc[m][0][r] + bm0);
                const float msg = softplus_f(acc[m][1][r] + bg0);
                laggr[row][j0] = gate * msg;
            }
            {
                const float gate = sigmoid_f(acc[m][2][r] + bm1);
                const float msg = softplus_f(acc[m][3][r] + bg1);
                laggr[row][j0 + 16] = gate * msg;
            }
        }
    }
    __syncthreads();

    // ---- epilogue B: column-walk segment reduce, one atomic per (segment-run, col) ----
    {
        const int col = t & 127;
        const int r0 = (t >> 7) * 16;
        float s = 0.f;
        #pragma unroll
        for (int r = r0; r < r0 + 16; ++r) {
            s += laggr[r][col];
            if ((r == r0 + 15) || (sdsts[r + 1] != sdsts[r])) {   // short-circuit: no OOB
                atomicAdd(aggr + (size_t)sdsts[r] * HID + col, s);
                s = 0.f;
            }
        }
    }
}

__global__ void update_kernel(_Float16* __restrict__ h, const float* __restrict__ aggr) {
    const size_t idx = (size_t)blockIdx.x * blockDim.x + threadIdx.x;   // half8 index
    half8 hv = ((const half8*)h)[idx];
    const f32x4 a0 = ((const f32x4*)aggr)[2 * idx];
    const f32x4 a1 = ((const f32x4*)aggr)[2 * idx + 1];
    #pragma unroll
    for (int j = 0; j < 4; ++j) hv[j] = (_Float16)softplus_f((float)hv[j] + a0[j]);
    #pragma unroll
    for (int j = 0; j < 4; ++j) hv[4 + j] = (_Float16)softplus_f((float)hv[4 + j] + a1[j]);
    ((half8*)h)[idx] = hv;
}

__global__ void readout_kernel(const _Float16* __restrict__ h, const int* __restrict__ batch,
                               const float* __restrict__ ro1w, const float* __restrict__ ro1b,
                               const float* __restrict__ ro2w, const float* __restrict__ ro2b,
                               float* __restrict__ out) {
    __shared__ float pooled[HID];
    __shared__ float red[HID];
    __shared__ int range[2];
    const int g = blockIdx.x, j = threadIdx.x;
    if (j == 0) {
        int lo = 0, hi = NNODES;
        while (lo < hi) { int mid = (lo + hi) >> 1; if (batch[mid] < g) lo = mid + 1; else hi = mid; }
        range[0] = lo;
        hi = NNODES;
        while (lo < hi) { int mid = (lo + hi) >> 1; if (batch[mid] < g + 1) lo = mid + 1; else hi = mid; }
        range[1] = lo;
    }
    __syncthreads();
    const int start = range[0], end = range[1];
    float s = 0.f;
    for (int n = start; n < end; ++n) s += (float)h[(size_t)n * HID + j];
    const float cnt = (float)(end - start);
    pooled[j] = s / fmaxf(cnt, 1.f);
    __syncthreads();
    float acc = ro1b[j];
    #pragma unroll 4
    for (int k = 0; k < HID; ++k) acc = fmaf(pooled[k], ro1w[k * HID + j], acc);
    red[j] = softplus_f(acc) * ro2w[j];
    __syncthreads();
    for (int sdt = 64; sdt > 0; sdt >>= 1) {
        if (j < sdt) red[j] += red[j + sdt];
        __syncthreads();
    }
    if (j == 0) out[g] = red[0] + ro2b[0];
}

extern "C" void kernel_launch(void* const* d_in, const int* in_sizes, int n_in,
                              void* d_out, int out_size, void* d_ws, size_t ws_size,
                              hipStream_t stream) {
    (void)in_sizes; (void)n_in; (void)out_size; (void)ws_size;
    const float* x      = (const float*)d_in[0];
    const int*   ei     = (const int*)d_in[1];
    const float* ea     = (const float*)d_in[2];
    const int*   batch  = (const int*)d_in[3];
    const float* emb_w  = (const float*)d_in[4];
    const float* emb_b  = (const float*)d_in[5];
    const float* msg_w  = (const float*)d_in[6];
    const float* msg_b  = (const float*)d_in[7];
    const float* gate_w = (const float*)d_in[8];
    const float* gate_b = (const float*)d_in[9];
    const float* ro1w   = (const float*)d_in[10];
    const float* ro1b   = (const float*)d_in[11];
    const float* ro2w   = (const float*)d_in[12];
    const float* ro2b   = (const float*)d_in[13];
    float* out = (float*)d_out;

    // workspace: h(f16) 12.8MB + aggr(f32) 25.6MB + wfrag 0.49MB + perm 6.4MB = 45.3MB
    _Float16* h  = (_Float16*)d_ws;
    float* aggr  = (float*)(h + (size_t)NNODES * HID);
    half8* wfrag = (half8*)(aggr + (size_t)NNODES * HID);
    int* perm    = (int*)(wfrag + (size_t)NCONV * 16 * KSTEPS * 64);
    int* counts  = (int*)aggr;   // aliased: sort finishes before aggr's first memset

    // one-time dst counting sort of edges (produces perm only)
    hipMemsetAsync(counts, 0, (size_t)NNODES * sizeof(int), stream);
    hist_kernel<<<(NEDGES + 255) / 256, 256, 0, stream>>>(ei, counts);
    scan_kernel<<<1, SCAN_T, 0, stream>>>(counts);
    scatter_kernel<<<(NEDGES + 255) / 256, 256, 0, stream>>>(ei, counts, perm);

    const int wtotal = NCONV * 16 * KSTEPS * 64;
    prep_wfrag<<<(wtotal + 255) / 256, 256, 0, stream>>>(msg_w, gate_w, wfrag);
    embed_kernel<<<NNODES, HID, 0, stream>>>(x, emb_w, emb_b, h);

    for (int l = 0; l < NCONV; ++l) {
        hipMemsetAsync(aggr, 0, (size_t)NNODES * HID * sizeof(float), stream);
        edge_mfma_kernel<<<NEDGES / ME, 256, 0, stream>>>(
            h, ei, perm, ea, wfrag + (size_t)l * 16 * KSTEPS * 64,
            msg_b + l * HID, gate_b + l * HID, aggr);
        update_kernel<<<((size_t)NNODES * HID / 8) / 256, 256, 0, stream>>>(h, aggr);
    }

    readout_kernel<<<NGRAPHS, HID, 0, stream>>>(h, batch, ro1w, ro1b, ro2w, ro2b, out);
}